// Round 1
// baseline (183.383 us; speedup 1.0000x reference)
//
#include <hip/hip_runtime.h>
#include <math.h>

// Problem shapes (fixed by setup_inputs)
#define B 64
#define T 512
#define D 768   // = 3 * 256
#define V 20
#define NEG -1000000000.0f
#define TCH 32          // tokens per chunk
#define NCH (T / TCH)   // 16 chunks

// ---------------------------------------------------------------------------
// Kernel A: masked partial sums over token chunks.
// part[(b*NCH+c)*D + d] = sum over tt in chunk c of mask[b,t]*emb[b,t,d]
// grid = B*NCH blocks, 256 threads; each thread owns 3 d-columns.
// Wave-uniform skip of masked tokens (~50% of global reads avoided).
// ---------------------------------------------------------------------------
__global__ __launch_bounds__(256) void k_masked_sum(
    const float* __restrict__ emb, const int* __restrict__ emask,
    float* __restrict__ part) {
  int b = blockIdx.x / NCH;
  int c = blockIdx.x % NCH;
  int tid = threadIdx.x;
  __shared__ int sm[TCH];
  if (tid < TCH) sm[tid] = emask[b * T + c * TCH + tid];
  __syncthreads();
  float a0 = 0.f, a1 = 0.f, a2 = 0.f;
  const float* eb = emb + (size_t)b * T * D + (size_t)c * TCH * D;
  for (int tt = 0; tt < TCH; ++tt) {
    if (sm[tt]) {  // wave-uniform branch
      const float* e = eb + (size_t)tt * D + tid;
      a0 += e[0];
      a1 += e[256];
      a2 += e[512];
    }
  }
  float* p = part + (size_t)blockIdx.x * D + tid;
  p[0] = a0;
  p[256] = a1;
  p[512] = a2;
}

// ---------------------------------------------------------------------------
// Kernel B: per-batch — reduce partials, value scores (V dots of D),
// softmax over V, value_probs out, value_embedding out.
// grid = B blocks, 256 threads (4 waves).
// ---------------------------------------------------------------------------
__global__ __launch_bounds__(256) void k_value(
    const float* __restrict__ part, const int* __restrict__ vmask,
    const float* __restrict__ W, float* __restrict__ out_vemb,
    float* __restrict__ out_vprobs) {
  int b = blockIdx.x;
  int tid = threadIdx.x;
  __shared__ float msum[D];
  __shared__ float sc[V];
  __shared__ float pr[V];
  for (int k = 0; k < 3; ++k) {
    int d = tid + 256 * k;
    float s = 0.f;
    for (int c = 0; c < NCH; ++c) s += part[((size_t)(b * NCH + c)) * D + d];
    msum[d] = s;
  }
  __syncthreads();
  int wave = tid >> 6, lane = tid & 63;
  for (int v = wave; v < V; v += 4) {
    float p = 0.f;
    for (int j = 0; j < 12; ++j) {
      int d = lane + 64 * j;
      p += msum[d] * W[(size_t)v * D + d];
    }
    for (int off = 32; off; off >>= 1) p += __shfl_down(p, off, 64);
    if (lane == 0) sc[v] = p + (vmask[b * V + v] ? 0.f : NEG);
  }
  __syncthreads();
  if (tid == 0) {
    float m = sc[0];
    for (int v = 1; v < V; ++v) m = fmaxf(m, sc[v]);
    float s = 0.f;
    for (int v = 0; v < V; ++v) {
      float e = expf(sc[v] - m);
      pr[v] = e;
      s += e;
    }
    float inv = 1.f / s;
    for (int v = 0; v < V; ++v) {
      pr[v] *= inv;
      out_vprobs[b * V + v] = pr[v];
    }
  }
  __syncthreads();
  for (int k = 0; k < 3; ++k) {
    int d = tid + 256 * k;
    float a = 0.f;
    for (int v = 0; v < V; ++v) a += pr[v] * W[(size_t)v * D + d];
    out_vemb[(size_t)b * D + d] = a;
  }
}

// ---------------------------------------------------------------------------
// Kernel C: pooling scores. One wave per (b,t); 64-lane shuffle dot over D.
// Masked tokens short-circuit to NEG (exp underflows to exactly 0 either way,
// matching the reference's dot+NEG).
// grid = B*T/4 blocks, 256 threads (4 waves).
// ---------------------------------------------------------------------------
__global__ __launch_bounds__(256) void k_pool_scores(
    const float* __restrict__ emb, const int* __restrict__ emask,
    const float* __restrict__ vemb, float* __restrict__ scores) {
  int wave = threadIdx.x >> 6, lane = threadIdx.x & 63;
  int w = blockIdx.x * 4 + wave;
  int b = w >> 9;  // T = 512
  int t = w & 511;
  if (emask[b * T + t] == 0) {
    if (lane == 0) scores[b * T + t] = NEG;
    return;
  }
  const float* e = emb + ((size_t)b * T + t) * D;
  const float* ve = vemb + (size_t)b * D;
  float p = 0.f;
  for (int j = 0; j < 12; ++j) {
    int d = lane + 64 * j;
    p += e[d] * ve[d];
  }
  for (int off = 32; off; off >>= 1) p += __shfl_down(p, off, 64);
  if (lane == 0) scores[b * T + t] = p;
}

// ---------------------------------------------------------------------------
// Kernel D1: softmax over T per batch. grid = B, 256 threads (2 t each).
// ---------------------------------------------------------------------------
__global__ __launch_bounds__(256) void k_softmax_T(
    const float* __restrict__ scores, float* __restrict__ probs) {
  int b = blockIdx.x, tid = threadIdx.x;
  int wave = tid >> 6, lane = tid & 63;
  float s0 = scores[b * T + tid];
  float s1 = scores[b * T + 256 + tid];
  float m = fmaxf(s0, s1);
  __shared__ float redm[4];
  __shared__ float reds[4];
  for (int off = 32; off; off >>= 1) m = fmaxf(m, __shfl_down(m, off, 64));
  if (lane == 0) redm[wave] = m;
  __syncthreads();
  m = fmaxf(fmaxf(redm[0], redm[1]), fmaxf(redm[2], redm[3]));
  float e0 = expf(s0 - m), e1 = expf(s1 - m);
  float s = e0 + e1;
  for (int off = 32; off; off >>= 1) s += __shfl_down(s, off, 64);
  if (lane == 0) reds[wave] = s;
  __syncthreads();
  s = reds[0] + reds[1] + reds[2] + reds[3];
  float inv = 1.f / s;
  probs[b * T + tid] = e0 * inv;
  probs[b * T + 256 + tid] = e1 * inv;
}

// ---------------------------------------------------------------------------
// Kernel D2: prob-weighted partial sums (same shape as kernel A).
// Skips exactly-zero-prob tokens (all masked tokens) wave-uniformly.
// ---------------------------------------------------------------------------
__global__ __launch_bounds__(256) void k_pool_partial(
    const float* __restrict__ emb, const float* __restrict__ probs,
    float* __restrict__ part) {
  int b = blockIdx.x / NCH;
  int c = blockIdx.x % NCH;
  int tid = threadIdx.x;
  __shared__ float wts[TCH];
  if (tid < TCH) wts[tid] = probs[b * T + c * TCH + tid];
  __syncthreads();
  float a0 = 0.f, a1 = 0.f, a2 = 0.f;
  const float* eb = emb + (size_t)b * T * D + (size_t)c * TCH * D;
  for (int tt = 0; tt < TCH; ++tt) {
    float wv = wts[tt];
    if (wv != 0.f) {  // wave-uniform branch
      const float* e = eb + (size_t)tt * D + tid;
      a0 += wv * e[0];
      a1 += wv * e[256];
      a2 += wv * e[512];
    }
  }
  float* p = part + (size_t)blockIdx.x * D + tid;
  p[0] = a0;
  p[256] = a1;
  p[512] = a2;
}

// ---------------------------------------------------------------------------
// Kernel D3: reduce pooled partials -> pooled_embedding. grid = B.
// ---------------------------------------------------------------------------
__global__ __launch_bounds__(256) void k_reduce_part(
    const float* __restrict__ part, float* __restrict__ pooled) {
  int b = blockIdx.x, tid = threadIdx.x;
  for (int k = 0; k < 3; ++k) {
    int d = tid + 256 * k;
    float s = 0.f;
    for (int c = 0; c < NCH; ++c) s += part[((size_t)(b * NCH + c)) * D + d];
    pooled[(size_t)b * D + d] = s;
  }
}

extern "C" void kernel_launch(void* const* d_in, const int* in_sizes, int n_in,
                              void* d_out, int out_size, void* d_ws,
                              size_t ws_size, hipStream_t stream) {
  const float* emb = (const float*)d_in[0];    // (B,T,D)
  const int* emask = (const int*)d_in[1];      // (B,T)
  const int* vmask = (const int*)d_in[2];      // (B,V)
  const float* W = (const float*)d_in[3];      // (V,D)

  float* out = (float*)d_out;
  float* vemb_out = out;                         // B*D
  float* pooled_out = out + B * D;               // B*D
  float* vprobs_out = out + 2 * B * D;           // B*V
  float* pprobs_out = out + 2 * B * D + B * V;   // B*T

  float* ws = (float*)d_ws;
  float* part = ws;                  // B*NCH*D floats
  float* scores = ws + B * NCH * D;  // B*T floats

  k_masked_sum<<<B * NCH, 256, 0, stream>>>(emb, emask, part);
  k_value<<<B, 256, 0, stream>>>(part, vmask, W, vemb_out, vprobs_out);
  k_pool_scores<<<B * T / 4, 256, 0, stream>>>(emb, emask, vemb_out, scores);
  k_softmax_T<<<B, 256, 0, stream>>>(scores, pprobs_out);
  k_pool_partial<<<B * NCH, 256, 0, stream>>>(emb, pprobs_out, part);
  k_reduce_part<<<B, 256, 0, stream>>>(part, pooled_out);
}

// Round 2
// 171.746 us; speedup vs baseline: 1.0678x; 1.0678x over previous
//
#include <hip/hip_runtime.h>
#include <math.h>

// Problem shapes (fixed by setup_inputs)
#define B 64
#define T 512
#define D 768          // = 192 float4
#define D4 (D / 4)     // 192
#define V 20
#define NEG -1000000000.0f
#define TCH 32         // tokens per chunk
#define NCH (T / TCH)  // 16 chunks

// ---------------------------------------------------------------------------
// Kernel A: masked partial sums over token chunks, float4-vectorized.
// 192 threads (3 waves); thread owns one float4 column. Wave-uniform skip of
// masked tokens (~50% of emb reads avoided).
// ---------------------------------------------------------------------------
__global__ __launch_bounds__(192) void k_masked_sum(
    const float4* __restrict__ emb4, const int* __restrict__ emask,
    float4* __restrict__ part4) {
  int b = blockIdx.x / NCH;
  int c = blockIdx.x % NCH;
  int tid = threadIdx.x;
  __shared__ int sm[TCH];
  if (tid < TCH) sm[tid] = emask[b * T + c * TCH + tid];
  __syncthreads();
  float4 a = {0.f, 0.f, 0.f, 0.f};
  const float4* eb = emb4 + ((size_t)b * T + (size_t)c * TCH) * D4 + tid;
  for (int tt = 0; tt < TCH; ++tt) {
    if (sm[tt]) {  // wave-uniform branch
      float4 e = eb[(size_t)tt * D4];
      a.x += e.x; a.y += e.y; a.z += e.z; a.w += e.w;
    }
  }
  part4[(size_t)blockIdx.x * D4 + tid] = a;
}

// ---------------------------------------------------------------------------
// Kernel B: per-batch — reduce partials, V=20 dots of D, softmax over V,
// value_probs + value_embedding. grid = B, 256 threads. Tiny.
// ---------------------------------------------------------------------------
__global__ __launch_bounds__(256) void k_value(
    const float* __restrict__ part, const int* __restrict__ vmask,
    const float* __restrict__ W, float* __restrict__ out_vemb,
    float* __restrict__ out_vprobs) {
  int b = blockIdx.x;
  int tid = threadIdx.x;
  __shared__ float msum[D];
  __shared__ float sc[V];
  __shared__ float pr[V];
  for (int k = 0; k < 3; ++k) {
    int d = tid + 256 * k;
    float s = 0.f;
    for (int c = 0; c < NCH; ++c) s += part[((size_t)(b * NCH + c)) * D + d];
    msum[d] = s;
  }
  __syncthreads();
  int wave = tid >> 6, lane = tid & 63;
  for (int v = wave; v < V; v += 4) {
    float p = 0.f;
    for (int j = 0; j < 12; ++j) {
      int d = lane + 64 * j;
      p += msum[d] * W[(size_t)v * D + d];
    }
    for (int off = 32; off; off >>= 1) p += __shfl_down(p, off, 64);
    if (lane == 0) sc[v] = p + (vmask[b * V + v] ? 0.f : NEG);
  }
  __syncthreads();
  if (tid == 0) {
    float m = sc[0];
    for (int v = 1; v < V; ++v) m = fmaxf(m, sc[v]);
    float s = 0.f;
    for (int v = 0; v < V; ++v) {
      float e = expf(sc[v] - m);
      pr[v] = e;
      s += e;
    }
    float inv = 1.f / s;
    for (int v = 0; v < V; ++v) {
      pr[v] *= inv;
      out_vprobs[b * V + v] = pr[v];
    }
  }
  __syncthreads();
  for (int k = 0; k < 3; ++k) {
    int d = tid + 256 * k;
    float a = 0.f;
    for (int v = 0; v < V; ++v) a += pr[v] * W[(size_t)v * D + d];
    out_vemb[(size_t)b * D + d] = a;
  }
}

// ---------------------------------------------------------------------------
// Kernel C (fused): pooling scores + per-chunk online-softmax weighted
// accumulation, ONE pass over emb. One wave per token iteration; the emb
// fragment loaded for the dot is reused (still in registers) for the
// exp-weighted accumulator. Per-chunk (m_c, l_c, acc_c[D]) -> ws; raw scores
// -> ws for the finalizer. grid = B*NCH, 256 threads (4 waves).
// ---------------------------------------------------------------------------
__global__ __launch_bounds__(256) void k_fused_pool(
    const float4* __restrict__ emb4, const int* __restrict__ emask,
    const float4* __restrict__ vemb4, float* __restrict__ scores,
    float* __restrict__ pm, float* __restrict__ pl,
    float4* __restrict__ pacc4) {
  int b = blockIdx.x / NCH;
  int c = blockIdx.x % NCH;
  int tid = threadIdx.x;
  int wave = tid >> 6, lane = tid & 63;
  __shared__ int sm[TCH];
  __shared__ float lm[4], ll[4];
  __shared__ float lacc[4][D];  // 12 KB
  if (tid < TCH) sm[tid] = emask[b * T + c * TCH + tid];
  __syncthreads();

  // per-lane fragment of value_embedding[b] (fixed across tokens)
  float4 ve[3];
  for (int j = 0; j < 3; ++j) ve[j] = vemb4[(size_t)b * D4 + lane + 64 * j];

  float m = NEG, l = 0.f;
  float4 acc[3];
  for (int j = 0; j < 3; ++j) acc[j] = {0.f, 0.f, 0.f, 0.f};

  const float4* eb = emb4 + ((size_t)b * T + (size_t)c * TCH) * D4;
  for (int tt = wave; tt < TCH; tt += 4) {
    if (!sm[tt]) {  // wave-uniform
      if (lane == 0) scores[b * T + c * TCH + tt] = NEG;
      continue;
    }
    float4 e[3];
    for (int j = 0; j < 3; ++j) e[j] = eb[(size_t)tt * D4 + lane + 64 * j];
    float p = 0.f;
    for (int j = 0; j < 3; ++j)
      p += e[j].x * ve[j].x + e[j].y * ve[j].y + e[j].z * ve[j].z +
           e[j].w * ve[j].w;
    for (int off = 32; off; off >>= 1) p += __shfl_xor(p, off, 64);
    if (lane == 0) scores[b * T + c * TCH + tt] = p;
    // online softmax update (p is wave-uniform after butterfly)
    if (p > m) {
      float scale = expf(m - p);
      l *= scale;
      for (int j = 0; j < 3; ++j) {
        acc[j].x *= scale; acc[j].y *= scale;
        acc[j].z *= scale; acc[j].w *= scale;
      }
      m = p;
    }
    float w = expf(p - m);
    l += w;
    for (int j = 0; j < 3; ++j) {
      acc[j].x += w * e[j].x; acc[j].y += w * e[j].y;
      acc[j].z += w * e[j].z; acc[j].w += w * e[j].w;
    }
  }

  // combine the 4 waves via LDS
  if (lane == 0) { lm[wave] = m; ll[wave] = l; }
  for (int j = 0; j < 3; ++j)
    *(float4*)&lacc[wave][4 * (lane + 64 * j)] = acc[j];
  __syncthreads();

  __shared__ float co[4];
  __shared__ float sM, sL;
  if (tid == 0) {
    float M = fmaxf(fmaxf(lm[0], lm[1]), fmaxf(lm[2], lm[3]));
    float L = 0.f;
    for (int w2 = 0; w2 < 4; ++w2) {
      co[w2] = expf(lm[w2] - M);
      L += ll[w2] * co[w2];
    }
    sM = M; sL = L;
    pm[blockIdx.x] = M;
    pl[blockIdx.x] = L;
  }
  __syncthreads();
  if (tid < D4) {
    float4 s = {0.f, 0.f, 0.f, 0.f};
    for (int w2 = 0; w2 < 4; ++w2) {
      float cw = co[w2];
      float4 a = *(float4*)&lacc[w2][4 * tid];
      s.x += cw * a.x; s.y += cw * a.y; s.z += cw * a.z; s.w += cw * a.w;
    }
    pacc4[(size_t)blockIdx.x * D4 + tid] = s;
  }
}

// ---------------------------------------------------------------------------
// Kernel D: per-batch finalize — combine chunk (m,l,acc), write
// pooled_embedding and pooling_probs. grid = B, 256 threads. Tiny.
// ---------------------------------------------------------------------------
__global__ __launch_bounds__(256) void k_pool_final(
    const float* __restrict__ pm, const float* __restrict__ pl,
    const float* __restrict__ pacc, const float* __restrict__ scores,
    const int* __restrict__ emask, float* __restrict__ pooled,
    float* __restrict__ pprobs) {
  int b = blockIdx.x, tid = threadIdx.x;
  __shared__ float co[NCH];
  __shared__ float sM, sinvL;
  if (tid == 0) {
    float M = NEG;
    for (int c = 0; c < NCH; ++c) M = fmaxf(M, pm[b * NCH + c]);
    float L = 0.f;
    for (int c = 0; c < NCH; ++c) L += pl[b * NCH + c] * expf(pm[b * NCH + c] - M);
    float invL = 1.f / L;
    for (int c = 0; c < NCH; ++c) co[c] = expf(pm[b * NCH + c] - M) * invL;
    sM = M; sinvL = invL;
  }
  __syncthreads();
  for (int k = 0; k < 3; ++k) {
    int d = tid + 256 * k;
    float s = 0.f;
    for (int c = 0; c < NCH; ++c) s += pacc[((size_t)(b * NCH + c)) * D + d] * co[c];
    pooled[(size_t)b * D + d] = s;
  }
  for (int k = 0; k < 2; ++k) {
    int t = tid + 256 * k;
    pprobs[b * T + t] =
        emask[b * T + t] ? expf(scores[b * T + t] - sM) * sinvL : 0.f;
  }
}

extern "C" void kernel_launch(void* const* d_in, const int* in_sizes, int n_in,
                              void* d_out, int out_size, void* d_ws,
                              size_t ws_size, hipStream_t stream) {
  const float* emb = (const float*)d_in[0];    // (B,T,D)
  const int* emask = (const int*)d_in[1];      // (B,T)
  const int* vmask = (const int*)d_in[2];      // (B,V)
  const float* W = (const float*)d_in[3];      // (V,D)

  float* out = (float*)d_out;
  float* vemb_out = out;                        // B*D
  float* pooled_out = out + B * D;              // B*D
  float* vprobs_out = out + 2 * B * D;          // B*V
  float* pprobs_out = out + 2 * B * D + B * V;  // B*T

  float* ws = (float*)d_ws;
  float* part = ws;                       // B*NCH*D floats (reused as pacc)
  float* scores = ws + B * NCH * D;       // B*T floats
  float* pm = scores + B * T;             // B*NCH
  float* pl = pm + B * NCH;               // B*NCH

  k_masked_sum<<<B * NCH, 192, 0, stream>>>((const float4*)emb, emask,
                                            (float4*)part);
  k_value<<<B, 256, 0, stream>>>(part, vmask, W, vemb_out, vprobs_out);
  // part is dead after k_value; k_fused_pool reuses it as pacc
  k_fused_pool<<<B * NCH, 256, 0, stream>>>((const float4*)emb, emask,
                                            (const float4*)vemb_out, scores, pm,
                                            pl, (float4*)part);
  k_pool_final<<<B, 256, 0, stream>>>(pm, pl, part, scores, emask, pooled_out,
                                      pprobs_out);
}